// Round 9
// baseline (2661.636 us; speedup 1.0000x reference)
//
#include <hip/hip_runtime.h>
#include <cstddef>
#include <cstdint>

#define WSLOPE 0.2f
#define WEPS 1e-12f

typedef __attribute__((ext_vector_type(8))) short bf16x8;
typedef __attribute__((ext_vector_type(4))) float f32x4;
typedef __attribute__((ext_vector_type(2))) float f32x2;

__device__ __forceinline__ float waveSum(float v) {
#pragma unroll
    for (int off = 32; off > 0; off >>= 1) v += __shfl_xor(v, off, 64);
    return v;
}
// reduce across the 16 llo lanes (same lhi group)
__device__ __forceinline__ float rowSum16(float v) {
#pragma unroll
    for (int off = 8; off > 0; off >>= 1) v += __shfl_xor(v, off, 64);
    return v;
}
__device__ __forceinline__ float eluf(float v) { return v > 0.f ? v : expm1f(v); }
__device__ __forceinline__ short f2bf(float f) {
    union { float f; uint32_t u; } v; v.f = f;
    uint32_t r = v.u + 0x7FFF + ((v.u >> 16) & 1);
    return (short)(r >> 16);
}
__device__ __forceinline__ float bf2f(short s) {
    union { uint32_t u; float f; } v; v.u = ((uint32_t)(uint16_t)s) << 16;
    return v.f;
}

// ---------------- node prep: invnorm + xn_bf + hop1 node dots packed (one pass over x) ----------------
// ndi[n] = {r_h0, r_h1, c_h0, c_h1} for in-weights; ndo likewise for out-weights
__global__ void k_nodeprep(const float* __restrict__ x, short* __restrict__ xnb,
                           const float* __restrict__ wai, const float* __restrict__ wao,
                           f32x4* __restrict__ ndi, f32x4* __restrict__ ndo, int N) {
    int wid = blockIdx.x * 4 + (threadIdx.x >> 6);
    int lane = threadIdx.x & 63;
    if (wid >= N) return;
    const float* p = x + (size_t)wid * 100;
    float a0 = p[lane];
    float a1 = (lane < 36) ? p[lane + 64] : 0.f;
    float ss = waveSum(a0 * a0 + a1 * a1);
    float inv = 1.f / fmaxf(sqrtf(ss), WEPS);
    float f0 = a0 * inv, f1 = a1 * inv;
    short* xb = xnb + (size_t)wid * 112;
    xb[lane] = f2bf(f0);
    if (lane < 36) xb[64 + lane] = f2bf(f1);
    else if (lane < 48) xb[64 + lane] = 0;
    float rI[2], cI[2], rO[2], cO[2];
#pragma unroll
    for (int h = 0; h < 2; ++h) {
        const float* wi = wai + h * 300;
        const float* wo = wao + h * 300;
        float ri = f0 * wi[lane] + f1 * wi[lane + 64];
        float ci = f0 * wi[100 + lane] + f1 * wi[100 + lane + 64];
        float ro = f0 * wo[lane] + f1 * wo[lane + 64];
        float co = f0 * wo[100 + lane] + f1 * wo[100 + lane + 64];
        rI[h] = waveSum(ri); cI[h] = waveSum(ci); rO[h] = waveSum(ro); cO[h] = waveSum(co);
    }
    if (lane == 0) {
        ndi[wid] = f32x4{rI[0], rI[1], cI[0], cI[1]};
        ndo[wid] = f32x4{rO[0], rO[1], cO[0], cO[1]};
    }
}

// ---------------- type prep: g_bf + gcomb g-half + hop1 g dots (one pass over g) ----------------
// gcomb row stride = 416: cols 0..99 g bf16, 100..111 pad
__global__ void k_gprep(const float* __restrict__ g, short* __restrict__ gbf,
                        short* __restrict__ gcomb,
                        const float* __restrict__ wai, const float* __restrict__ wao,
                        float* __restrict__ gdi, float* __restrict__ gdo, int M) {
    int m = blockIdx.x * 4 + (threadIdx.x >> 6);
    int lane = threadIdx.x & 63;
    if (m >= M) return;
    const float* gm = g + (size_t)m * 100;
    float v0 = gm[lane];
    float v1 = (lane < 36) ? gm[lane + 64] : 0.f;
    short b0 = f2bf(v0), b1 = (lane < 36) ? f2bf(v1) : (short)0;
    short* gb = gbf + (size_t)m * 112;
    gb[lane] = b0;
    if (lane < 48) gb[64 + lane] = (lane < 36) ? b1 : (short)0;
    short* gc = gcomb + (size_t)m * 416;
    gc[lane] = b0;
    if (lane < 48) gc[64 + lane] = (lane < 36) ? b1 : (short)0;   // cols 64..111 (100..111 = 0)
    float s0 = v0 * wai[200 + lane];
    float s1 = v0 * wai[500 + lane];
    float s2 = v0 * wao[200 + lane];
    float s3 = v0 * wao[500 + lane];
    if (lane < 36) {
        s0 += v1 * wai[264 + lane]; s1 += v1 * wai[564 + lane];
        s2 += v1 * wao[264 + lane]; s3 += v1 * wao[564 + lane];
    }
    s0 = waveSum(s0); s1 = waveSum(s1); s2 = waveSum(s2); s3 = waveSum(s3);
    if (lane == 0) { gdi[m * 2] = s0; gdi[m * 2 + 1] = s1; gdo[m * 2] = s2; gdo[m * 2 + 1] = s3; }
}

// ---------------- generic CSR build (counting sort) ----------------
__global__ void k_count(const int* __restrict__ keys, int* __restrict__ cnt, int n) {
    int i = blockIdx.x * 256 + threadIdx.x;
    if (i < n) atomicAdd(&cnt[keys[i]], 1);
}

#define SCAN_CHUNK 2048
__global__ void k_blocksum(const int* __restrict__ cnt, int* __restrict__ bsum, int n) {
    __shared__ int sh[256];
    int b = blockIdx.x, t = threadIdx.x;
    int base = b * SCAN_CHUNK;
    int s = 0;
    for (int i = t; i < SCAN_CHUNK; i += 256) { int idx = base + i; if (idx < n) s += cnt[idx]; }
    sh[t] = s; __syncthreads();
    for (int off = 128; off > 0; off >>= 1) { if (t < off) sh[t] += sh[t + off]; __syncthreads(); }
    if (t == 0) bsum[b] = sh[0];
}

__global__ void k_scanwrite(const int* __restrict__ cnt, const int* __restrict__ bsum,
                            int* __restrict__ offs, int* __restrict__ cur, int n, int nb) {
    __shared__ int sh[256];
    __shared__ int sbase;
    int b = blockIdx.x, t = threadIdx.x;
    if (t == 0) { int s = 0; for (int i = 0; i < b; ++i) s += bsum[i]; sbase = s; }
    __syncthreads();
    int base = b * SCAN_CHUNK;
    int loc[8]; int ts = 0;
#pragma unroll
    for (int i = 0; i < 8; ++i) { int idx = base + t * 8 + i; int v = (idx < n) ? cnt[idx] : 0; loc[i] = ts; ts += v; }
    sh[t] = ts; __syncthreads();
    for (int off = 1; off < 256; off <<= 1) {
        int v = (t >= off) ? sh[t - off] : 0;
        __syncthreads();
        sh[t] += v;
        __syncthreads();
    }
    int excl = (t == 0) ? 0 : sh[t - 1];
    int gbase = sbase + excl;
#pragma unroll
    for (int i = 0; i < 8; ++i) {
        int idx = base + t * 8 + i;
        if (idx < n) { offs[idx] = gbase + loc[i]; cur[idx] = gbase + loc[i]; }
    }
    if (b == nb - 1 && t == 255) offs[n] = sbase + sh[255];
}

__global__ void k_scatter3(const int* __restrict__ keys, const int* __restrict__ other,
                           const int* __restrict__ et, int* __restrict__ cur,
                           int* __restrict__ nbrS, int* __restrict__ etS,
                           int* __restrict__ keyS, int n) {
    int i = blockIdx.x * 256 + threadIdx.x;
    if (i < n) {
        int p = atomicAdd(&cur[keys[i]], 1);
        nbrS[p] = other[i];
        etS[p] = et[i];
        keyS[p] = keys[i];
    }
}

__global__ void k_scatter2(const int* __restrict__ keys, int* __restrict__ cur,
                           int* __restrict__ rs, int* __restrict__ cs,
                           const int* __restrict__ row, const int* __restrict__ col, int n) {
    int i = blockIdx.x * 256 + threadIdx.x;
    if (i < n) {
        int p = atomicAdd(&cur[keys[i]], 1);
        rs[p] = row[i];
        cs[p] = col[i];
    }
}

// ---------------- attention vector ----------------
__global__ void k_watt(const float* __restrict__ att, const float* __restrict__ W,
                       float* __restrict__ wa, int H, int DH, int K) {
    int id = blockIdx.x * 256 + threadIdx.x;
    if (id >= H * K) return;
    int h = id / K, k = id % K;
    float s = 0.f;
    for (int j = 0; j < DH; ++j) s += att[h * DH + j] * W[(size_t)(h * DH + j) * K + k];
    wa[id] = s;
}

// ---------------- hop1 per-edge weights (packed node dots) ----------------
__global__ void k_ewh1(const int* __restrict__ nbi, const int* __restrict__ kyi,
                       const int* __restrict__ eti,
                       const int* __restrict__ nbo, const int* __restrict__ kyo,
                       const int* __restrict__ eto,
                       const f32x4* __restrict__ ndi, const f32x4* __restrict__ ndo,
                       const float* __restrict__ gdi, const float* __restrict__ gdo,
                       float* __restrict__ ewi, float* __restrict__ ewo, int E) {
    int id = blockIdx.x * 256 + threadIdx.x;
    int tot = E * 2;
    if (id >= 2 * tot) return;
    if (id < tot) {
        int p = id >> 1, h = id & 1;
        f32x4 n1 = ndi[nbi[p]];
        f32x4 n2 = ndi[kyi[p]];
        float a = (h ? n1.y : n1.x) + (h ? n2.w : n2.z) + gdi[eti[p] * 2 + h];
        float lr = a > 0.f ? a : WSLOPE * a;
        ewi[id] = expf(-lr);
    } else {
        int id2 = id - tot;
        int p = id2 >> 1, h = id2 & 1;
        f32x4 n1 = ndo[nbo[p]];
        f32x4 n2 = ndo[kyo[p]];
        float a = (h ? n1.w : n1.z) + (h ? n2.y : n2.x) + gdo[eto[p] * 2 + h];
        float lr = a > 0.f ? a : WSLOPE * a;
        ewo[id2] = expf(-lr);
    }
}

// ---------------- hop2 per-edge weights (packed nd2 + gd2) ----------------
// nd2[n] = {ri, ci, ro, co}; gd2[m] = {gi, go}
__global__ void k_ewh2(const int* __restrict__ nbi, const int* __restrict__ kyi,
                       const int* __restrict__ eti,
                       const int* __restrict__ nbo, const int* __restrict__ kyo,
                       const int* __restrict__ eto,
                       const f32x4* __restrict__ nd2, const f32x2* __restrict__ gd2,
                       float* __restrict__ ewi, float* __restrict__ ewo, int E) {
    int id = blockIdx.x * 256 + threadIdx.x;
    if (id >= 2 * E) return;
    if (id < E) {
        f32x4 n1 = nd2[nbi[id]];
        f32x4 n2 = nd2[kyi[id]];
        float a = n1.x + n2.y + gd2[eti[id]].x;
        float lr = a > 0.f ? a : WSLOPE * a;
        ewi[id] = expf(-lr);
    } else {
        int p = id - E;
        f32x4 n1 = nd2[nbo[p]];
        f32x4 n2 = nd2[kyo[p]];
        float a = n1.w + n2.z + gd2[eto[p]].y;
        float lr = a > 0.f ? a : WSLOPE * a;
        ewo[p] = expf(-lr);
    }
}

// ---------------- CSR aggregation: both directions in one launch ----------------
// wave per node; per direction writes A row = [agg 224 | z 224] (self read by GEMM from table)
template<bool HOP2>
__global__ void k_agg2(const int* __restrict__ offsI, const int* __restrict__ nbrI,
                       const int* __restrict__ etI, const float* __restrict__ ewI,
                       const int* __restrict__ offsO, const int* __restrict__ nbrO,
                       const int* __restrict__ etO, const float* __restrict__ ewO,
                       const short* __restrict__ featB, const short* __restrict__ gB,
                       short* __restrict__ A0, short* __restrict__ A1, int n0, int n1) {
    constexpr int H = HOP2 ? 1 : 2;
    constexpr int LDA = 448;
    constexpr int FW = HOP2 ? 224 : 112;
    constexpr int GW = HOP2 ? 224 : 112;
    int node = n0 + blockIdx.x * 4 + (threadIdx.x >> 6);
    int lane = threadIdx.x & 63;
    if (node >= n1) return;
#pragma unroll 1
    for (int dir = 0; dir < 2; ++dir) {
        const int* offs = dir ? offsO : offsI;
        const int* nbrS = dir ? nbrO : nbrI;
        const int* etS  = dir ? etO  : etI;
        const float* ewS = dir ? ewO : ewI;
        short* A = dir ? A1 : A0;
        int o = offs[node];
        int deg = offs[node + 1] - o;
        float va[7];
#pragma unroll
        for (int m = 0; m < 7; ++m) va[m] = 0.f;
        if (deg > 0) {
            float s0 = 0.f, s1 = 0.f;
            for (int i = lane; i < deg; i += 64) {
                s0 += ewS[(size_t)(o + i) * H];
                if (H == 2) s1 += ewS[(size_t)(o + i) * H + 1];
            }
            s0 = waveSum(s0);
            float rd0 = 1.f / s0, rd1 = rd0;
            if (H == 2) { s1 = waveSum(s1); rd1 = 1.f / s1; }
            for (int j = 0; j < deg; ++j) {
                float a0 = ewS[(size_t)(o + j) * H] * rd0;
                float a1 = (H == 2) ? ewS[(size_t)(o + j) * H + 1] * rd1 : a0;
                int nbr = nbrS[o + j];
                int et = etS[o + j];
                const short* fr = featB + (size_t)nbr * FW;
                const short* gr = gB + (size_t)et * GW;
                if (!HOP2) {
#pragma unroll
                    for (int m = 0; m < 7; ++m) {
                        int d = lane + m * 64;
                        if (d < 100) va[m] += a0 * bf2f(fr[d]);
                        else if (d < 200) va[m] += a1 * bf2f(fr[d - 100]);
                        else if (d < 300) va[m] += a0 * bf2f(gr[d - 200]);
                        else if (d < 400) va[m] += a1 * bf2f(gr[d - 300]);
                    }
                } else {
#pragma unroll
                    for (int m = 0; m < 7; ++m) {
                        int d = lane + m * 64;
                        if (d < 200) va[m] += a0 * bf2f(fr[d]);
                        else if (d < 424) va[m] += a0 * bf2f(gr[d - 200]);
                    }
                }
            }
        }
        size_t rb = (size_t)(node - n0);
        short* Ar = A + rb * LDA;
        if (!HOP2) {
#pragma unroll
            for (int m = 0; m < 7; ++m) {
                int d = lane + m * 64;
                if (d < 400) {
                    int col = d < 100 ? d : (d < 200 ? d + 12 : (d < 300 ? d + 24 : d + 36));
                    Ar[col] = f2bf(va[m]);
                }
            }
            if (lane < 48) { int q = lane / 12; int rm = lane - q * 12; Ar[q * 112 + 100 + rm] = 0; }
        } else {
#pragma unroll
            for (int m = 0; m < 7; ++m) {
                int d = lane + m * 64;
                if (d < 424) Ar[d < 200 ? d : d + 24] = f2bf(va[m]);
            }
            if (lane < 24) Ar[200 + lane] = 0;
        }
    }
}

// ---------------- agg GEMM: A = [Ac 448 | self from table] ; fused elu + l2norm -> bf16 post ----------------
template<int KS_S, int H>
__launch_bounds__(256)
__global__ void k_mgemm_post(const short* __restrict__ A, const short* __restrict__ Wb,
                             const short* __restrict__ selfB, int selfLD,
                             const int* __restrict__ offs,
                             short* __restrict__ post, int rows) {
    constexpr int KS_A = 14;
    constexpr int LDW = (KS_A + KS_S) * 32;
    const int t = threadIdx.x;
    const int wv = t >> 6, l = t & 63;
    const int lhi = l >> 4, llo = l & 15;
    const int rbase = blockIdx.x * 64 + wv * 16;
    const int ra = rbase + llo;
    const int deg = (ra < rows) ? (offs[ra + 1] - offs[ra]) : 0;
    f32x4 acc[13];
#pragma unroll
    for (int j = 0; j < 13; ++j) acc[j] = f32x4{0.f, 0.f, 0.f, 0.f};
    const short* arow = A + (size_t)ra * 448 + lhi * 8;
#pragma unroll
    for (int kt = 0; kt < KS_A; ++kt) {
        bf16x8 a = *(const bf16x8*)(arow + kt * 32);
#pragma unroll
        for (int j = 0; j < 13; ++j) {
            bf16x8 b = *(const bf16x8*)(Wb + (size_t)(j * 16 + llo) * LDW + kt * 32 + lhi * 8);
            acc[j] = __builtin_amdgcn_mfma_f32_16x16x32_bf16(a, b, acc[j], 0, 0, 0);
        }
    }
    const short* srow = selfB + (size_t)ra * selfLD + lhi * 8;
#pragma unroll
    for (int kt = 0; kt < KS_S; ++kt) {
        bf16x8 a;
        if (deg > 0) a = *(const bf16x8*)(srow + kt * 32);
        else a = bf16x8{0, 0, 0, 0, 0, 0, 0, 0};
#pragma unroll
        for (int j = 0; j < 13; ++j) {
            bf16x8 b = *(const bf16x8*)(Wb + (size_t)(j * 16 + llo) * LDW + (KS_A + kt) * 32 + lhi * 8);
            acc[j] = __builtin_amdgcn_mfma_f32_16x16x32_bf16(a, b, acc[j], 0, 0, 0);
        }
    }
    const int r0 = rbase + lhi * 4;
#pragma unroll
    for (int e = 0; e < 4; ++e) {
        int r = r0 + e;
        if (r >= rows) continue;
        float v[13];
        float s0 = 0.f, s1 = 0.f;
#pragma unroll
        for (int j = 0; j < 13; ++j) {
            int d = j * 16 + llo;
            if (d < 200) {
                float xv = eluf(acc[j][e]);
                v[j] = xv;
                if (H == 1 || d < 100) s0 += xv * xv; else s1 += xv * xv;
            }
        }
        s0 = rowSum16(s0);
        float inv0 = 1.f / fmaxf(sqrtf(s0), WEPS);
        float inv1 = inv0;
        if (H == 2) { s1 = rowSum16(s1); inv1 = 1.f / fmaxf(sqrtf(s1), WEPS); }
        short* pr = post + (size_t)r * 224;
#pragma unroll
        for (int j = 0; j < 13; ++j) {
            int d = j * 16 + llo;
            if (d < 200) pr[d] = f2bf(v[j] * ((H == 2 && d >= 100) ? inv1 : inv0));
        }
    }
}

// ---------------- fused merge v2: 512 threads, column tiles split across wave pairs ----------------
template<bool HOP1>
__launch_bounds__(512)
__global__ void k_mergemm2(const short* __restrict__ pA, const short* __restrict__ pB,
                           const short* __restrict__ Wi, const short* __restrict__ Wo,
                           const float* __restrict__ bi, const float* __restrict__ bo,
                           const float* __restrict__ Wl, const float* __restrict__ bl,
                           const short* __restrict__ xnb, const short* __restrict__ Went,
                           float* __restrict__ outf, short* __restrict__ h1b,
                           const float* __restrict__ wa2i, const float* __restrict__ wa2o,
                           f32x4* __restrict__ nd2,
                           int rows) {
    __shared__ float lpS[2][64];
    __shared__ float ssS[2][64];
    __shared__ float dotS[2][64][4];
    const int t = threadIdx.x;
    const int wvAll = t >> 6;          // 0..7
    const int rg = wvAll >> 1;         // row group 0..3 (16 rows each)
    const int half = wvAll & 1;        // column half
    const int l = t & 63;
    const int lhi = l >> 4, llo = l & 15;
    const int jbase = half * 7;        // tiles jbase..jbase+6 (half1: 7..12 => 6 tiles)
    const int rbase = blockIdx.x * 64 + rg * 16;
    f32x4 accA[7], accB[7];
#pragma unroll
    for (int j = 0; j < 7; ++j) { accA[j] = f32x4{0.f, 0.f, 0.f, 0.f}; accB[j] = f32x4{0.f, 0.f, 0.f, 0.f}; }
    const short* pa = pA + (size_t)(rbase + llo) * 224 + lhi * 8;
    const short* pb = pB + (size_t)(rbase + llo) * 224 + lhi * 8;
#pragma unroll
    for (int kt = 0; kt < 7; ++kt) {
        bf16x8 a1 = *(const bf16x8*)(pa + kt * 32);
        bf16x8 a2 = *(const bf16x8*)(pb + kt * 32);
#pragma unroll
        for (int j = 0; j < 7; ++j) {
            if (jbase + j < 13) {
                bf16x8 b1 = *(const bf16x8*)(Wi + (size_t)((jbase + j) * 16 + llo) * 224 + kt * 32 + lhi * 8);
                accA[j] = __builtin_amdgcn_mfma_f32_16x16x32_bf16(a1, b1, accA[j], 0, 0, 0);
                bf16x8 b2 = *(const bf16x8*)(Wo + (size_t)((jbase + j) * 16 + llo) * 224 + kt * 32 + lhi * 8);
                accB[j] = __builtin_amdgcn_mfma_f32_16x16x32_bf16(a2, b2, accB[j], 0, 0, 0);
            }
        }
    }
    // entity residual (hop2 only)
    f32x4 accR[7];
    if (!HOP1) {
#pragma unroll
        for (int j = 0; j < 7; ++j) accR[j] = f32x4{0.f, 0.f, 0.f, 0.f};
        const short* xr = xnb + (size_t)(rbase + llo) * 112 + lhi * 8;
#pragma unroll
        for (int kt = 0; kt < 4; ++kt) {
            bf16x8 a = *(const bf16x8*)(xr + kt * 32);
#pragma unroll
            for (int j = 0; j < 7; ++j) {
                if (jbase + j < 13) {
                    bf16x8 b = *(const bf16x8*)(Went + (size_t)((jbase + j) * 16 + llo) * 128 + kt * 32 + lhi * 8);
                    accR[j] = __builtin_amdgcn_mfma_f32_16x16x32_bf16(a, b, accR[j], 0, 0, 0);
                }
            }
        }
    }
    const int r0 = rbase + lhi * 4;
    const int rrb = rg * 16 + lhi * 4;
    float blv = bl[0];
    // phase A: lambda logit partials
#pragma unroll
    for (int e = 0; e < 4; ++e) {
        float lp = 0.f;
#pragma unroll
        for (int j = 0; j < 7; ++j) {
            int d = (jbase + j) * 16 + llo;
            if (jbase + j < 13 && d < 200)
                lp += Wl[d] * (accA[j][e] + bi[d]) + Wl[200 + d] * (accB[j][e] + bo[d]);
        }
        lp = rowSum16(lp);
        if (llo == 0) lpS[half][rrb + e] = lp;
    }
    __syncthreads();
    // phase B: lambda, elu, norm partials
    float lamAll[4];
#pragma unroll
    for (int e = 0; e < 4; ++e) {
        float lam = 1.f / (1.f + expf(-(lpS[0][rrb + e] + lpS[1][rrb + e] + blv)));
        lamAll[e] = lam;
        float ss = 0.f;
#pragma unroll
        for (int j = 0; j < 7; ++j) {
            int d = (jbase + j) * 16 + llo;
            if (jbase + j < 13 && d < 200) {
                float vi = accA[j][e] + bi[d];
                float vo = accB[j][e] + bo[d];
                float hv = eluf(lam * vi + (1.f - lam) * vo);
                ss += hv * hv;
            }
        }
        ss = rowSum16(ss);
        if (llo == 0) ssS[half][rrb + e] = ss;
    }
    __syncthreads();
    // phase C: final write (+ hop2 attention dots in hop1 mode)
#pragma unroll
    for (int e = 0; e < 4; ++e) {
        int r = r0 + e;
        if (r >= rows) continue;
        float inv = 1.f / fmaxf(sqrtf(ssS[0][rrb + e] + ssS[1][rrb + e]), WEPS);
        float lam = lamAll[e];
        float ri = 0.f, ci = 0.f, ro = 0.f, co = 0.f;
#pragma unroll
        for (int j = 0; j < 7; ++j) {
            if (jbase + j >= 13) continue;
            int d = (jbase + j) * 16 + llo;
            if (d < 200) {
                float vi = accA[j][e] + bi[d];
                float vo = accB[j][e] + bo[d];
                float val = eluf(lam * vi + (1.f - lam) * vo) * inv;
                if (HOP1) {
                    h1b[(size_t)r * 224 + d] = f2bf(val);
                    ri += val * wa2i[d]; ci += val * wa2i[200 + d];
                    ro += val * wa2o[d]; co += val * wa2o[200 + d];
                } else {
                    outf[(size_t)r * 200 + d] = val + accR[j][e];
                }
            } else if (HOP1) {
                h1b[(size_t)r * 224 + d] = 0;   // d in [200,208)
            }
        }
        if (HOP1) {
            if (half) h1b[(size_t)r * 224 + 208 + llo] = 0;
            ri = rowSum16(ri); ci = rowSum16(ci); ro = rowSum16(ro); co = rowSum16(co);
            if (llo == 0) {
                dotS[half][rrb + e][0] = ri; dotS[half][rrb + e][1] = ci;
                dotS[half][rrb + e][2] = ro; dotS[half][rrb + e][3] = co;
            }
        }
    }
    if (HOP1) {
        __syncthreads();
        if (half == 0 && llo == 0) {
#pragma unroll
            for (int e = 0; e < 4; ++e) {
                int r = r0 + e;
                if (r < rows) {
                    nd2[r] = f32x4{dotS[0][rrb + e][0] + dotS[1][rrb + e][0],
                                   dotS[0][rrb + e][1] + dotS[1][rrb + e][1],
                                   dotS[0][rrb + e][2] + dotS[1][rrb + e][2],
                                   dotS[0][rrb + e][3] + dotS[1][rrb + e][3]};
                }
            }
        }
    }
}

// ---------------- relation GEMM: fused bias + bf16 gp write + packed hop2 gdots (lda 416) ----------------
__launch_bounds__(256)
__global__ void k_mgemm_rel(const short* __restrict__ A, const short* __restrict__ Wb,
                            const float* __restrict__ brf,
                            short* __restrict__ gout, const float* __restrict__ wai,
                            const float* __restrict__ wao,
                            f32x2* __restrict__ gd2, int rows) {
    constexpr int KSTEPS = 13, LDW = KSTEPS * 32;
    const int t = threadIdx.x;
    const int wv = t >> 6, l = t & 63;
    const int lhi = l >> 4, llo = l & 15;
    const int rbase = blockIdx.x * 64 + wv * 16;
    f32x4 acc[13];
#pragma unroll
    for (int j = 0; j < 13; ++j) acc[j] = f32x4{0.f, 0.f, 0.f, 0.f};
    const short* arow = A + (size_t)(rbase + llo) * 416 + lhi * 8;
#pragma unroll
    for (int kt = 0; kt < KSTEPS; ++kt) {
        bf16x8 a = *(const bf16x8*)(arow + kt * 32);
#pragma unroll
        for (int j = 0; j < 13; ++j) {
            bf16x8 b = *(const bf16x8*)(Wb + (size_t)(j * 16 + llo) * LDW + kt * 32 + lhi * 8);
            acc[j] = __builtin_amdgcn_mfma_f32_16x16x32_bf16(a, b, acc[j], 0, 0, 0);
        }
    }
    const int r0 = rbase + lhi * 4;
#pragma unroll
    for (int e = 0; e < 4; ++e) {
        int r = r0 + e;
        if (r >= rows) continue;
        short* pr = gout + (size_t)r * 224;
        float gi = 0.f, go = 0.f;
#pragma unroll
        for (int j = 0; j < 13; ++j) {
            int d = j * 16 + llo;
            if (d < 200) {
                float val = acc[j][e] + brf[d];
                pr[d] = f2bf(val);
                gi += val * wai[400 + d];
                go += val * wao[400 + d];
            } else {
                pr[d] = 0;   // d in [200,208)
            }
        }
        pr[208 + llo] = 0;
        gi = rowSum16(gi); go = rowSum16(go);
        if (llo == 0) gd2[r] = f32x2{gi, go};
    }
}

// ---------------- weight prep ----------------
__global__ void k_prepw(const float* __restrict__ W, int ldW, int koff, int Klen, int span,
                        int mode, short* __restrict__ Wb, int ldWb, int dst) {
    int id = blockIdx.x * 256 + threadIdx.x;
    int tot = 208 * span;
    if (id >= tot) return;
    int d = id / span, k = id - d * span;
    float v = 0.f;
    if (d < 200) {
        if (mode == 0) { if (k < Klen) v = W[(size_t)d * ldW + koff + k]; }
        else { int h = d / 100; int kk = k - h * 112; if (kk >= 0 && kk < Klen) v = W[(size_t)d * ldW + koff + kk]; }
    }
    Wb[(size_t)d * ldWb + dst + k] = f2bf(v);
}

// combined [Wr | pad | Wf] -> bf16 [208][416]  (cols 0..99 = Wr, 112..411 = Wf)
__global__ void k_prepwrf(const float* __restrict__ Wr, const float* __restrict__ Wf,
                          short* __restrict__ Wb) {
    int id = blockIdx.x * 256 + threadIdx.x;
    if (id >= 208 * 416) return;
    int d = id / 416, k = id - d * 416;
    float v = 0.f;
    if (d < 200) {
        if (k < 100) v = Wr[(size_t)d * 100 + k];
        else if (k >= 112 && k < 412) v = Wf[(size_t)d * 300 + (k - 112)];
    }
    Wb[id] = f2bf(v);
}

__global__ void k_brf(const float* __restrict__ br, const float* __restrict__ bf,
                      float* __restrict__ brf) {
    int d = threadIdx.x;
    if (d < 200) brf[d] = br[d] + bf[d];
}

// ---------------- relation layer: block per type, 384 threads (all gathers from bf16 tables) ----------------
__global__ void k_gedges_b(const int* __restrict__ rsT, const int* __restrict__ csT,
                           const int* __restrict__ offsT,
                           const short* __restrict__ xnb,
                           const short* __restrict__ gbf, short* __restrict__ gcomb, int M) {
    __shared__ float red[6];
    int m = blockIdx.x, t = threadIdx.x;
    int o = offsT[m];
    int deg = offsT[m + 1] - o;
    float acc = 0.f;
    if (t < 128) {
        int d = t; bool ok = d < 100;
        for (int i = 0; i < deg; ++i) {
            int r = rsT[o + i];
            if (ok) acc += bf2f(xnb[(size_t)r * 112 + d]);
        }
    } else if (t < 256) {
        int d = t - 128; bool ok = d < 100;
        for (int i = 0; i < deg; ++i) {
            int c = csT[o + i];
            if (ok) acc += bf2f(xnb[(size_t)c * 112 + d]);
        }
    } else {
        int d = t - 256;
        if (d < 100) acc = (float)deg * bf2f(gbf[(size_t)m * 112 + d]);
    }
    float sq = waveSum(acc * acc);
    if ((t & 63) == 0) red[t >> 6] = sq;
    __syncthreads();
    float s2 = red[0] + red[1] + red[2] + red[3] + red[4] + red[5];
    float inv = 1.f / fmaxf(sqrtf(s2), WEPS);
    short* orow = gcomb + (size_t)m * 416 + 112;
    if (t < 128) {
        if (t < 100) orow[t] = f2bf(eluf(acc * inv));
    } else if (t < 256) {
        int d = t - 128;
        if (d < 100) orow[100 + d] = f2bf(eluf(acc * inv));
    } else {
        int d = t - 256;
        if (d < 100) orow[200 + d] = f2bf(eluf(acc * inv));
        else if (d < 104) orow[200 + d] = 0;   // pad cols 300..303
    }
}

// ---------------- host launch ----------------
extern "C" void kernel_launch(void* const* d_in, const int* in_sizes, int n_in,
                              void* d_out, int out_size, void* d_ws, size_t ws_size,
                              hipStream_t stream) {
    const int* eidx   = (const int*)d_in[0];
    const int* etype  = (const int*)d_in[1];
    const float* x    = (const float*)d_in[5];
    const float* g    = (const float*)d_in[6];
    const float* W_in1  = (const float*)d_in[7];
    const float* att_in1 = (const float*)d_in[8];
    const float* W_out1 = (const float*)d_in[9];
    const float* att_out1 = (const float*)d_in[10];
    const float* Wi1 = (const float*)d_in[11]; const float* bi1 = (const float*)d_in[12];
    const float* Wo1 = (const float*)d_in[13]; const float* bo1 = (const float*)d_in[14];
    const float* Wl1 = (const float*)d_in[15]; const float* bl1 = (const float*)d_in[16];
    const float* Wr  = (const float*)d_in[17]; const float* br  = (const float*)d_in[18];
    const float* Wf  = (const float*)d_in[19]; const float* bf  = (const float*)d_in[20];
    const float* W_in2  = (const float*)d_in[21]; const float* att_in2 = (const float*)d_in[22];
    const float* W_out2 = (const float*)d_in[23]; const float* att_out2 = (const float*)d_in[24];
    const float* Wi2 = (const float*)d_in[25]; const float* bi2 = (const float*)d_in[26];
    const float* Wo2 = (const float*)d_in[27]; const float* bo2 = (const float*)d_in[28];
    const float* Wl2 = (const float*)d_in[29]; const float* bl2 = (const float*)d_in[30];
    const float* W_ent = (const float*)d_in[31];

    const int E = in_sizes[1];
    const int N = in_sizes[5] / 100;
    const int M = in_sizes[6] / 100;
    const int Mr = (M + 63) & ~63;
    float* out = (float*)d_out;
    const int* row = eidx;
    const int* col = eidx + E;

    char* w = (char*)d_ws;
    size_t off_b = 0;
    auto alloc = [&](size_t bytes) -> void* {
        void* p = w + off_b;
        off_b += (bytes + 255) & ~(size_t)255;
        return p;
    };
    short* h1_bf = (short*)alloc((size_t)(N + 64) * 224 * 2);
    short* xn_bf = (short*)alloc((size_t)(N + 64) * 112 * 2);
    short* g_bf  = (short*)alloc((size_t)M * 112 * 2);
    short* gp_bf = (short*)alloc((size_t)Mr * 224 * 2);
    int* offs_in = (int*)alloc((size_t)(N + 1) * 4);
    int* offs_out= (int*)alloc((size_t)(N + 1) * 4);
    int* offsT   = (int*)alloc((size_t)(M + 1) * 4);
    int* nbrS_in = (int*)alloc((size_t)E * 4);
    int* etS_in  = (int*)alloc((size_t)E * 4);
    int* keyS_in = (int*)alloc((size_t)E * 4);
    int* nbrS_out= (int*)alloc((size_t)E * 4);
    int* etS_out = (int*)alloc((size_t)E * 4);
    int* keyS_out= (int*)alloc((size_t)E * 4);
    int* rsT     = (int*)alloc((size_t)E * 4);
    int* csT     = (int*)alloc((size_t)E * 4);
    int* cnt     = (int*)alloc((size_t)N * 4);
    int* cur     = (int*)alloc((size_t)N * 4);
    int* bsum    = (int*)alloc((size_t)64 * 4);
    float* wa1_in = (float*)alloc((size_t)640 * 4);
    float* wa1_out= (float*)alloc((size_t)640 * 4);
    float* wa2_in = (float*)alloc((size_t)640 * 4);
    float* wa2_out= (float*)alloc((size_t)640 * 4);
    f32x4* nd1i  = (f32x4*)alloc((size_t)N * 16);
    f32x4* nd1o  = (f32x4*)alloc((size_t)N * 16);
    f32x4* nd2   = (f32x4*)alloc((size_t)N * 16);
    float* gdot_in = (float*)alloc((size_t)M * 2 * 4);
    float* gdot_out= (float*)alloc((size_t)M * 2 * 4);
    f32x2* gd2   = (f32x2*)alloc((size_t)M * 8);
    float* ewS_in  = (float*)alloc((size_t)E * 2 * 4);
    float* ewS_out = (float*)alloc((size_t)E * 2 * 4);
    // relation A buffer [Mr][416]: cols 0..111 g bf16(+pad), 112..415 ge_n bf16(+pad)
    short* gcomb   = (short*)alloc((size_t)Mr * 416 * 2);
    // bf16 weight buffers
    short* Wc_in1  = (short*)alloc((size_t)208 * 576 * 2);
    short* Wc_out1 = (short*)alloc((size_t)208 * 576 * 2);
    short* Wc_in2  = (short*)alloc((size_t)208 * 672 * 2);
    short* Wc_out2 = (short*)alloc((size_t)208 * 672 * 2);
    short* Wm_i1   = (short*)alloc((size_t)208 * 224 * 2);
    short* Wm_o1   = (short*)alloc((size_t)208 * 224 * 2);
    short* Wm_i2   = (short*)alloc((size_t)208 * 224 * 2);
    short* Wm_o2   = (short*)alloc((size_t)208 * 224 * 2);
    short* Wb_ent  = (short*)alloc((size_t)208 * 128 * 2);
    short* Wrf_b   = (short*)alloc((size_t)208 * 416 * 2);
    float* brf     = (float*)alloc((size_t)200 * 4);

    // chunk buffers: per-row 896(Ac0) + 896(Ac1) + 448(postA) + 448(postB) = 2688 B
    if (off_b >= ws_size) return;
    size_t rem = ws_size - off_b;
    long long Cll = (long long)(rem / 2816);
    long long Nr64 = ((long long)N + 63) & ~63LL;
    int C = (int)(Cll > Nr64 ? Nr64 : Cll);
    C &= ~63;
    if (C < 64) return;
    short* Ac0   = (short*)alloc((size_t)C * 448 * 2);
    short* Ac1   = (short*)alloc((size_t)C * 448 * 2);
    short* postA = (short*)alloc((size_t)C * 224 * 2);
    short* postB = (short*)alloc((size_t)C * 224 * 2);
    if (off_b > ws_size) return;

    const int gE = (E + 255) / 256;
    const int gN4 = (N + 3) / 4;
    const int gM4 = (M + 3) / 4;
    const int gM64 = (M + 63) / 64;

    // zero pad cols of post buffers + pad rows of feature tables (tail-tile reads)
    hipMemsetAsync(postA, 0, (size_t)C * 224 * 2, stream);
    hipMemsetAsync(postB, 0, (size_t)C * 224 * 2, stream);
    hipMemsetAsync(xn_bf + (size_t)N * 112, 0, (size_t)64 * 112 * 2, stream);
    hipMemsetAsync(h1_bf + (size_t)N * 224, 0, (size_t)64 * 224 * 2, stream);

    // ---- weight prep ----
    auto gsp = [](int span) { return (208 * span + 255) / 256; };
    k_prepw<<<gsp(224), 256, 0, stream>>>(W_in1, 300, 0, 100, 224, 1, Wc_in1, 576, 0);
    k_prepw<<<gsp(224), 256, 0, stream>>>(W_in1, 300, 200, 100, 224, 1, Wc_in1, 576, 224);
    k_prepw<<<gsp(128), 256, 0, stream>>>(W_in1, 300, 100, 100, 128, 0, Wc_in1, 576, 448);
    k_prepw<<<gsp(224), 256, 0, stream>>>(W_out1, 300, 100, 100, 224, 1, Wc_out1, 576, 0);
    k_prepw<<<gsp(224), 256, 0, stream>>>(W_out1, 300, 200, 100, 224, 1, Wc_out1, 576, 224);
    k_prepw<<<gsp(128), 256, 0, stream>>>(W_out1, 300, 0, 100, 128, 0, Wc_out1, 576, 448);
    k_prepw<<<gsp(224), 256, 0, stream>>>(W_in2, 600, 0, 200, 224, 0, Wc_in2, 672, 0);
    k_prepw<<<gsp(224), 256, 0, stream>>>(W_in2, 600, 400, 200, 224, 0, Wc_in2, 672, 224);
    k_prepw<<<gsp(224), 256, 0, stream>>>(W_in2, 600, 200, 200, 224, 0, Wc_in2, 672, 448);
    k_prepw<<<gsp(224), 256, 0, stream>>>(W_out2, 600, 200, 200, 224, 0, Wc_out2, 672, 0);
    k_prepw<<<gsp(224), 256, 0, stream>>>(W_out2, 600, 400, 200, 224, 0, Wc_out2, 672, 224);
    k_prepw<<<gsp(224), 256, 0, stream>>>(W_out2, 600, 0, 200, 224, 0, Wc_out2, 672, 448);
    k_prepw<<<gsp(224), 256, 0, stream>>>(Wi1, 200, 0, 200, 224, 0, Wm_i1, 224, 0);
    k_prepw<<<gsp(224), 256, 0, stream>>>(Wo1, 200, 0, 200, 224, 0, Wm_o1, 224, 0);
    k_prepw<<<gsp(224), 256, 0, stream>>>(Wi2, 200, 0, 200, 224, 0, Wm_i2, 224, 0);
    k_prepw<<<gsp(224), 256, 0, stream>>>(Wo2, 200, 0, 200, 224, 0, Wm_o2, 224, 0);
    k_prepw<<<gsp(128), 256, 0, stream>>>(W_ent, 100, 0, 100, 128, 0, Wb_ent, 128, 0);
    k_prepwrf<<<gsp(416), 256, 0, stream>>>(Wr, Wf, Wrf_b);
    k_brf<<<1, 256, 0, stream>>>(br, bf, brf);

    // ---- CSR builds with sorted payloads ----
    int nbN = (N + SCAN_CHUNK - 1) / SCAN_CHUNK;
    int nbM = (M + SCAN_CHUNK - 1) / SCAN_CHUNK;
    hipMemsetAsync(cnt, 0, (size_t)N * 4, stream);
    k_count<<<gE, 256, 0, stream>>>(col, cnt, E);
    k_blocksum<<<nbN, 256, 0, stream>>>(cnt, bsum, N);
    k_scanwrite<<<nbN, 256, 0, stream>>>(cnt, bsum, offs_in, cur, N, nbN);
    k_scatter3<<<gE, 256, 0, stream>>>(col, row, etype, cur, nbrS_in, etS_in, keyS_in, E);

    hipMemsetAsync(cnt, 0, (size_t)N * 4, stream);
    k_count<<<gE, 256, 0, stream>>>(row, cnt, E);
    k_blocksum<<<nbN, 256, 0, stream>>>(cnt, bsum, N);
    k_scanwrite<<<nbN, 256, 0, stream>>>(cnt, bsum, offs_out, cur, N, nbN);
    k_scatter3<<<gE, 256, 0, stream>>>(row, col, etype, cur, nbrS_out, etS_out, keyS_out, E);

    hipMemsetAsync(cnt, 0, (size_t)M * 4, stream);
    k_count<<<gE, 256, 0, stream>>>(etype, cnt, E);
    k_blocksum<<<nbM, 256, 0, stream>>>(cnt, bsum, M);
    k_scanwrite<<<nbM, 256, 0, stream>>>(cnt, bsum, offsT, cur, M, nbM);
    k_scatter2<<<gE, 256, 0, stream>>>(etype, cur, rsT, csT, row, col, E);

    // ---- attention vectors ----
    k_watt<<<(600 + 255) / 256, 256, 0, stream>>>(att_in1, W_in1, wa1_in, 2, 100, 300);
    k_watt<<<(600 + 255) / 256, 256, 0, stream>>>(att_out1, W_out1, wa1_out, 2, 100, 300);
    k_watt<<<(600 + 255) / 256, 256, 0, stream>>>(att_in2, W_in2, wa2_in, 1, 200, 600);
    k_watt<<<(600 + 255) / 256, 256, 0, stream>>>(att_out2, W_out2, wa2_out, 1, 200, 600);

    // ---- fused prep: one pass over x, one pass over g ----
    k_nodeprep<<<gN4, 256, 0, stream>>>(x, xn_bf, wa1_in, wa1_out, nd1i, nd1o, N);
    k_gprep<<<gM4, 256, 0, stream>>>(g, g_bf, gcomb, wa1_in, wa1_out, gdot_in, gdot_out, M);
    k_ewh1<<<(2 * E * 2 + 255) / 256, 256, 0, stream>>>(nbrS_in, keyS_in, etS_in,
                                                        nbrS_out, keyS_out, etS_out,
                                                        nd1i, nd1o, gdot_in, gdot_out,
                                                        ewS_in, ewS_out, E);

    for (int n0 = 0; n0 < N; n0 += C) {
        int rows = (N - n0 < C) ? (N - n0) : C;
        int n1 = n0 + rows;
        int ga = (rows + 3) / 4;
        int gb = (rows + 63) / 64;
        k_agg2<false><<<ga, 256, 0, stream>>>(offs_in, nbrS_in, etS_in, ewS_in,
                                              offs_out, nbrS_out, etS_out, ewS_out,
                                              xn_bf, g_bf, Ac0, Ac1, n0, n1);
        k_mgemm_post<4, 2><<<gb, 256, 0, stream>>>(Ac0, Wc_in1, xn_bf + (size_t)n0 * 112, 112,
                                                   offs_in + n0, postA, rows);
        k_mgemm_post<4, 2><<<gb, 256, 0, stream>>>(Ac1, Wc_out1, xn_bf + (size_t)n0 * 112, 112,
                                                   offs_out + n0, postB, rows);
        k_mergemm2<true><<<gb, 512, 0, stream>>>(postA, postB, Wm_i1, Wm_o1, bi1, bo1, Wl1, bl1,
                                                 nullptr, nullptr,
                                                 nullptr, h1_bf + (size_t)n0 * 224,
                                                 wa2_in, wa2_out, nd2 + n0, rows);
    }

    // ---- relation layer: segment sum + fused GEMM (bf16 gp + packed hop2 gdots) ----
    k_gedges_b<<<M, 384, 0, stream>>>(rsT, csT, offsT, xn_bf, g_bf, gcomb, M);
    k_mgemm_rel<<<gM64, 256, 0, stream>>>(gcomb, Wrf_b, brf, gp_bf, wa2_in, wa2_out, gd2, M);

    // ---- hop 2 edge weights (packed node/g dots) ----
    k_ewh2<<<(2 * E + 255) / 256, 256, 0, stream>>>(nbrS_in, keyS_in, etS_in,
                                                    nbrS_out, keyS_out, etS_out,
                                                    nd2, gd2, ewS_in, ewS_out, E);

    for (int n0 = 0; n0 < N; n0 += C) {
        int rows = (N - n0 < C) ? (N - n0) : C;
        int n1 = n0 + rows;
        int ga = (rows + 3) / 4;
        int gb = (rows + 63) / 64;
        k_agg2<true><<<ga, 256, 0, stream>>>(offs_in, nbrS_in, etS_in, ewS_in,
                                             offs_out, nbrS_out, etS_out, ewS_out,
                                             h1_bf, gp_bf, Ac0, Ac1, n0, n1);
        k_mgemm_post<7, 1><<<gb, 256, 0, stream>>>(Ac0, Wc_in2, h1_bf + (size_t)n0 * 224, 224,
                                                   offs_in + n0, postA, rows);
        k_mgemm_post<7, 1><<<gb, 256, 0, stream>>>(Ac1, Wc_out2, h1_bf + (size_t)n0 * 224, 224,
                                                   offs_out + n0, postB, rows);
        k_mergemm2<false><<<gb, 512, 0, stream>>>(postA, postB, Wm_i2, Wm_o2, bi2, bo2, Wl2, bl2,
                                                  xn_bf + (size_t)n0 * 112, Wb_ent,
                                                  out + (size_t)n0 * 200, nullptr,
                                                  nullptr, nullptr, nullptr, rows);
    }
}

// Round 10
// 2488.341 us; speedup vs baseline: 1.0696x; 1.0696x over previous
//
#include <hip/hip_runtime.h>
#include <cstddef>
#include <cstdint>

#define WSLOPE 0.2f
#define WEPS 1e-12f

typedef __attribute__((ext_vector_type(8))) short bf16x8;
typedef __attribute__((ext_vector_type(4))) float f32x4;
typedef __attribute__((ext_vector_type(2))) float f32x2;

__device__ __forceinline__ float waveSum(float v) {
#pragma unroll
    for (int off = 32; off > 0; off >>= 1) v += __shfl_xor(v, off, 64);
    return v;
}
// reduce across the 16 llo lanes (same lhi group)
__device__ __forceinline__ float rowSum16(float v) {
#pragma unroll
    for (int off = 8; off > 0; off >>= 1) v += __shfl_xor(v, off, 64);
    return v;
}
__device__ __forceinline__ float eluf(float v) { return v > 0.f ? v : expm1f(v); }
__device__ __forceinline__ short f2bf(float f) {
    union { float f; uint32_t u; } v; v.f = f;
    uint32_t r = v.u + 0x7FFF + ((v.u >> 16) & 1);
    return (short)(r >> 16);
}
__device__ __forceinline__ float bf2f(short s) {
    union { uint32_t u; float f; } v; v.u = ((uint32_t)(uint16_t)s) << 16;
    return v.f;
}

// ---------------- node prep: invnorm + xn_bf + hop1 node dots packed (one pass over x) ----------------
// ndi[n] = {r_h0, r_h1, c_h0, c_h1} for in-weights; ndo likewise for out-weights
__global__ void k_nodeprep(const float* __restrict__ x, short* __restrict__ xnb,
                           const float* __restrict__ wai, const float* __restrict__ wao,
                           f32x4* __restrict__ ndi, f32x4* __restrict__ ndo, int N) {
    int wid = blockIdx.x * 4 + (threadIdx.x >> 6);
    int lane = threadIdx.x & 63;
    if (wid >= N) return;
    const float* p = x + (size_t)wid * 100;
    float a0 = p[lane];
    float a1 = (lane < 36) ? p[lane + 64] : 0.f;
    float ss = waveSum(a0 * a0 + a1 * a1);
    float inv = 1.f / fmaxf(sqrtf(ss), WEPS);
    float f0 = a0 * inv, f1 = a1 * inv;
    short* xb = xnb + (size_t)wid * 112;
    xb[lane] = f2bf(f0);
    if (lane < 36) xb[64 + lane] = f2bf(f1);
    else if (lane < 48) xb[64 + lane] = 0;
    float rI[2], cI[2], rO[2], cO[2];
#pragma unroll
    for (int h = 0; h < 2; ++h) {
        const float* wi = wai + h * 300;
        const float* wo = wao + h * 300;
        float ri = f0 * wi[lane] + f1 * wi[lane + 64];
        float ci = f0 * wi[100 + lane] + f1 * wi[100 + lane + 64];
        float ro = f0 * wo[lane] + f1 * wo[lane + 64];
        float co = f0 * wo[100 + lane] + f1 * wo[100 + lane + 64];
        rI[h] = waveSum(ri); cI[h] = waveSum(ci); rO[h] = waveSum(ro); cO[h] = waveSum(co);
    }
    if (lane == 0) {
        ndi[wid] = f32x4{rI[0], rI[1], cI[0], cI[1]};
        ndo[wid] = f32x4{rO[0], rO[1], cO[0], cO[1]};
    }
}

// ---------------- type prep: g_bf + gcomb g-half + hop1 g dots (one pass over g) ----------------
// gcomb row stride = 416: cols 0..99 g bf16, 100..111 pad
__global__ void k_gprep(const float* __restrict__ g, short* __restrict__ gbf,
                        short* __restrict__ gcomb,
                        const float* __restrict__ wai, const float* __restrict__ wao,
                        float* __restrict__ gdi, float* __restrict__ gdo, int M) {
    int m = blockIdx.x * 4 + (threadIdx.x >> 6);
    int lane = threadIdx.x & 63;
    if (m >= M) return;
    const float* gm = g + (size_t)m * 100;
    float v0 = gm[lane];
    float v1 = (lane < 36) ? gm[lane + 64] : 0.f;
    short b0 = f2bf(v0), b1 = (lane < 36) ? f2bf(v1) : (short)0;
    short* gb = gbf + (size_t)m * 112;
    gb[lane] = b0;
    if (lane < 48) gb[64 + lane] = (lane < 36) ? b1 : (short)0;
    short* gc = gcomb + (size_t)m * 416;
    gc[lane] = b0;
    if (lane < 48) gc[64 + lane] = (lane < 36) ? b1 : (short)0;   // cols 64..111 (100..111 = 0)
    float s0 = v0 * wai[200 + lane];
    float s1 = v0 * wai[500 + lane];
    float s2 = v0 * wao[200 + lane];
    float s3 = v0 * wao[500 + lane];
    if (lane < 36) {
        s0 += v1 * wai[264 + lane]; s1 += v1 * wai[564 + lane];
        s2 += v1 * wao[264 + lane]; s3 += v1 * wao[564 + lane];
    }
    s0 = waveSum(s0); s1 = waveSum(s1); s2 = waveSum(s2); s3 = waveSum(s3);
    if (lane == 0) { gdi[m * 2] = s0; gdi[m * 2 + 1] = s1; gdo[m * 2] = s2; gdo[m * 2 + 1] = s3; }
}

// ---------------- generic CSR build (counting sort) ----------------
__global__ void k_count(const int* __restrict__ keys, int* __restrict__ cnt, int n) {
    int i = blockIdx.x * 256 + threadIdx.x;
    if (i < n) atomicAdd(&cnt[keys[i]], 1);
}

#define SCAN_CHUNK 2048
__global__ void k_blocksum(const int* __restrict__ cnt, int* __restrict__ bsum, int n) {
    __shared__ int sh[256];
    int b = blockIdx.x, t = threadIdx.x;
    int base = b * SCAN_CHUNK;
    int s = 0;
    for (int i = t; i < SCAN_CHUNK; i += 256) { int idx = base + i; if (idx < n) s += cnt[idx]; }
    sh[t] = s; __syncthreads();
    for (int off = 128; off > 0; off >>= 1) { if (t < off) sh[t] += sh[t + off]; __syncthreads(); }
    if (t == 0) bsum[b] = sh[0];
}

__global__ void k_scanwrite(const int* __restrict__ cnt, const int* __restrict__ bsum,
                            int* __restrict__ offs, int* __restrict__ cur, int n, int nb) {
    __shared__ int sh[256];
    __shared__ int sbase;
    int b = blockIdx.x, t = threadIdx.x;
    if (t == 0) { int s = 0; for (int i = 0; i < b; ++i) s += bsum[i]; sbase = s; }
    __syncthreads();
    int base = b * SCAN_CHUNK;
    int loc[8]; int ts = 0;
#pragma unroll
    for (int i = 0; i < 8; ++i) { int idx = base + t * 8 + i; int v = (idx < n) ? cnt[idx] : 0; loc[i] = ts; ts += v; }
    sh[t] = ts; __syncthreads();
    for (int off = 1; off < 256; off <<= 1) {
        int v = (t >= off) ? sh[t - off] : 0;
        __syncthreads();
        sh[t] += v;
        __syncthreads();
    }
    int excl = (t == 0) ? 0 : sh[t - 1];
    int gbase = sbase + excl;
#pragma unroll
    for (int i = 0; i < 8; ++i) {
        int idx = base + t * 8 + i;
        if (idx < n) { offs[idx] = gbase + loc[i]; cur[idx] = gbase + loc[i]; }
    }
    if (b == nb - 1 && t == 255) offs[n] = sbase + sh[255];
}

__global__ void k_scatter3(const int* __restrict__ keys, const int* __restrict__ other,
                           const int* __restrict__ et, int* __restrict__ cur,
                           int* __restrict__ nbrS, int* __restrict__ etS,
                           int* __restrict__ keyS, int n) {
    int i = blockIdx.x * 256 + threadIdx.x;
    if (i < n) {
        int p = atomicAdd(&cur[keys[i]], 1);
        nbrS[p] = other[i];
        etS[p] = et[i];
        keyS[p] = keys[i];
    }
}

__global__ void k_scatter2(const int* __restrict__ keys, int* __restrict__ cur,
                           int* __restrict__ rs, int* __restrict__ cs,
                           const int* __restrict__ row, const int* __restrict__ col, int n) {
    int i = blockIdx.x * 256 + threadIdx.x;
    if (i < n) {
        int p = atomicAdd(&cur[keys[i]], 1);
        rs[p] = row[i];
        cs[p] = col[i];
    }
}

// ---------------- attention vector ----------------
__global__ void k_watt(const float* __restrict__ att, const float* __restrict__ W,
                       float* __restrict__ wa, int H, int DH, int K) {
    int id = blockIdx.x * 256 + threadIdx.x;
    if (id >= H * K) return;
    int h = id / K, k = id % K;
    float s = 0.f;
    for (int j = 0; j < DH; ++j) s += att[h * DH + j] * W[(size_t)(h * DH + j) * K + k];
    wa[id] = s;
}

// ---------------- hop1 per-edge weights (packed node dots) ----------------
__global__ void k_ewh1(const int* __restrict__ nbi, const int* __restrict__ kyi,
                       const int* __restrict__ eti,
                       const int* __restrict__ nbo, const int* __restrict__ kyo,
                       const int* __restrict__ eto,
                       const f32x4* __restrict__ ndi, const f32x4* __restrict__ ndo,
                       const float* __restrict__ gdi, const float* __restrict__ gdo,
                       float* __restrict__ ewi, float* __restrict__ ewo, int E) {
    int id = blockIdx.x * 256 + threadIdx.x;
    int tot = E * 2;
    if (id >= 2 * tot) return;
    if (id < tot) {
        int p = id >> 1, h = id & 1;
        f32x4 n1 = ndi[nbi[p]];
        f32x4 n2 = ndi[kyi[p]];
        float a = (h ? n1.y : n1.x) + (h ? n2.w : n2.z) + gdi[eti[p] * 2 + h];
        float lr = a > 0.f ? a : WSLOPE * a;
        ewi[id] = expf(-lr);
    } else {
        int id2 = id - tot;
        int p = id2 >> 1, h = id2 & 1;
        f32x4 n1 = ndo[nbo[p]];
        f32x4 n2 = ndo[kyo[p]];
        float a = (h ? n1.w : n1.z) + (h ? n2.y : n2.x) + gdo[eto[p] * 2 + h];
        float lr = a > 0.f ? a : WSLOPE * a;
        ewo[id2] = expf(-lr);
    }
}

// ---------------- hop2 per-edge weights (packed nd2 + gd2) ----------------
// nd2[n] = {ri, ci, ro, co}; gd2[m] = {gi, go}
__global__ void k_ewh2(const int* __restrict__ nbi, const int* __restrict__ kyi,
                       const int* __restrict__ eti,
                       const int* __restrict__ nbo, const int* __restrict__ kyo,
                       const int* __restrict__ eto,
                       const f32x4* __restrict__ nd2, const f32x2* __restrict__ gd2,
                       float* __restrict__ ewi, float* __restrict__ ewo, int E) {
    int id = blockIdx.x * 256 + threadIdx.x;
    if (id >= 2 * E) return;
    if (id < E) {
        f32x4 n1 = nd2[nbi[id]];
        f32x4 n2 = nd2[kyi[id]];
        float a = n1.x + n2.y + gd2[eti[id]].x;
        float lr = a > 0.f ? a : WSLOPE * a;
        ewi[id] = expf(-lr);
    } else {
        int p = id - E;
        f32x4 n1 = nd2[nbo[p]];
        f32x4 n2 = nd2[kyo[p]];
        float a = n1.w + n2.z + gd2[eto[p]].y;
        float lr = a > 0.f ? a : WSLOPE * a;
        ewo[p] = expf(-lr);
    }
}

// ---------------- CSR aggregation: wave per node, bf16 gathers, A row = [agg 224 | z 224] ----------------
// self block not staged (GEMM reads feature table directly)
template<bool HOP2>
__global__ void k_agg(const int* __restrict__ offs, const int* __restrict__ nbrS,
                      const int* __restrict__ etS, const float* __restrict__ ewS,
                      const short* __restrict__ featB, const short* __restrict__ gB,
                      short* __restrict__ A, int n0, int n1) {
    constexpr int H = HOP2 ? 1 : 2;
    constexpr int LDA = 448;
    constexpr int FW = HOP2 ? 224 : 112;
    constexpr int GW = HOP2 ? 224 : 112;
    int node = n0 + blockIdx.x * 4 + (threadIdx.x >> 6);
    int lane = threadIdx.x & 63;
    if (node >= n1) return;
    int o = offs[node];
    int deg = offs[node + 1] - o;
    float va[7];
#pragma unroll
    for (int m = 0; m < 7; ++m) va[m] = 0.f;
    if (deg > 0) {
        float s0 = 0.f, s1 = 0.f;
        for (int i = lane; i < deg; i += 64) {
            s0 += ewS[(size_t)(o + i) * H];
            if (H == 2) s1 += ewS[(size_t)(o + i) * H + 1];
        }
        s0 = waveSum(s0);
        float rd0 = 1.f / s0, rd1 = rd0;
        if (H == 2) { s1 = waveSum(s1); rd1 = 1.f / s1; }
        for (int j = 0; j < deg; ++j) {
            float a0 = ewS[(size_t)(o + j) * H] * rd0;
            float a1 = (H == 2) ? ewS[(size_t)(o + j) * H + 1] * rd1 : a0;
            int nbr = nbrS[o + j];
            int et = etS[o + j];
            const short* fr = featB + (size_t)nbr * FW;
            const short* gr = gB + (size_t)et * GW;
            if (!HOP2) {
#pragma unroll
                for (int m = 0; m < 7; ++m) {
                    int d = lane + m * 64;
                    if (d < 100) va[m] += a0 * bf2f(fr[d]);
                    else if (d < 200) va[m] += a1 * bf2f(fr[d - 100]);
                    else if (d < 300) va[m] += a0 * bf2f(gr[d - 200]);
                    else if (d < 400) va[m] += a1 * bf2f(gr[d - 300]);
                }
            } else {
#pragma unroll
                for (int m = 0; m < 7; ++m) {
                    int d = lane + m * 64;
                    if (d < 200) va[m] += a0 * bf2f(fr[d]);
                    else if (d < 424) va[m] += a0 * bf2f(gr[d - 200]);
                }
            }
        }
    }
    size_t rb = (size_t)(node - n0);
    short* Ar = A + rb * LDA;
    if (!HOP2) {
#pragma unroll
        for (int m = 0; m < 7; ++m) {
            int d = lane + m * 64;
            if (d < 400) {
                int col = d < 100 ? d : (d < 200 ? d + 12 : (d < 300 ? d + 24 : d + 36));
                Ar[col] = f2bf(va[m]);
            }
        }
        if (lane < 48) { int q = lane / 12; int rm = lane - q * 12; Ar[q * 112 + 100 + rm] = 0; }
    } else {
#pragma unroll
        for (int m = 0; m < 7; ++m) {
            int d = lane + m * 64;
            if (d < 424) Ar[d < 200 ? d : d + 24] = f2bf(va[m]);
        }
        if (lane < 24) Ar[200 + lane] = 0;
    }
}

// ---------------- agg GEMM: A = [Ac 448 | self from table] ; fused elu + l2norm -> bf16 post ----------------
template<int KS_S, int H>
__launch_bounds__(256)
__global__ void k_mgemm_post(const short* __restrict__ A, const short* __restrict__ Wb,
                             const short* __restrict__ selfB, int selfLD,
                             const int* __restrict__ offs,
                             short* __restrict__ post, int rows) {
    constexpr int KS_A = 14;
    constexpr int LDW = (KS_A + KS_S) * 32;
    const int t = threadIdx.x;
    const int wv = t >> 6, l = t & 63;
    const int lhi = l >> 4, llo = l & 15;
    const int rbase = blockIdx.x * 64 + wv * 16;
    const int ra = rbase + llo;
    const int deg = (ra < rows) ? (offs[ra + 1] - offs[ra]) : 0;
    f32x4 acc[13];
#pragma unroll
    for (int j = 0; j < 13; ++j) acc[j] = f32x4{0.f, 0.f, 0.f, 0.f};
    const short* arow = A + (size_t)ra * 448 + lhi * 8;
#pragma unroll
    for (int kt = 0; kt < KS_A; ++kt) {
        bf16x8 a = *(const bf16x8*)(arow + kt * 32);
#pragma unroll
        for (int j = 0; j < 13; ++j) {
            bf16x8 b = *(const bf16x8*)(Wb + (size_t)(j * 16 + llo) * LDW + kt * 32 + lhi * 8);
            acc[j] = __builtin_amdgcn_mfma_f32_16x16x32_bf16(a, b, acc[j], 0, 0, 0);
        }
    }
    const short* srow = selfB + (size_t)ra * selfLD + lhi * 8;
#pragma unroll
    for (int kt = 0; kt < KS_S; ++kt) {
        bf16x8 a;
        if (deg > 0) a = *(const bf16x8*)(srow + kt * 32);
        else a = bf16x8{0, 0, 0, 0, 0, 0, 0, 0};
#pragma unroll
        for (int j = 0; j < 13; ++j) {
            bf16x8 b = *(const bf16x8*)(Wb + (size_t)(j * 16 + llo) * LDW + (KS_A + kt) * 32 + lhi * 8);
            acc[j] = __builtin_amdgcn_mfma_f32_16x16x32_bf16(a, b, acc[j], 0, 0, 0);
        }
    }
    const int r0 = rbase + lhi * 4;
#pragma unroll
    for (int e = 0; e < 4; ++e) {
        int r = r0 + e;
        if (r >= rows) continue;
        float v[13];
        float s0 = 0.f, s1 = 0.f;
#pragma unroll
        for (int j = 0; j < 13; ++j) {
            int d = j * 16 + llo;
            if (d < 200) {
                float xv = eluf(acc[j][e]);
                v[j] = xv;
                if (H == 1 || d < 100) s0 += xv * xv; else s1 += xv * xv;
            }
        }
        s0 = rowSum16(s0);
        float inv0 = 1.f / fmaxf(sqrtf(s0), WEPS);
        float inv1 = inv0;
        if (H == 2) { s1 = rowSum16(s1); inv1 = 1.f / fmaxf(sqrtf(s1), WEPS); }
        short* pr = post + (size_t)r * 224;
#pragma unroll
        for (int j = 0; j < 13; ++j) {
            int d = j * 16 + llo;
            if (d < 200) pr[d] = f2bf(v[j] * ((H == 2 && d >= 100) ? inv1 : inv0));
        }
    }
}

// ---------------- fused merge v2: 512 threads, column tiles split across wave pairs ----------------
template<bool HOP1>
__launch_bounds__(512)
__global__ void k_mergemm2(const short* __restrict__ pA, const short* __restrict__ pB,
                           const short* __restrict__ Wi, const short* __restrict__ Wo,
                           const float* __restrict__ bi, const float* __restrict__ bo,
                           const float* __restrict__ Wl, const float* __restrict__ bl,
                           const short* __restrict__ xnb, const short* __restrict__ Went,
                           float* __restrict__ outf, short* __restrict__ h1b,
                           const float* __restrict__ wa2i, const float* __restrict__ wa2o,
                           f32x4* __restrict__ nd2,
                           int rows) {
    __shared__ float lpS[2][64];
    __shared__ float ssS[2][64];
    __shared__ float dotS[2][64][4];
    const int t = threadIdx.x;
    const int wvAll = t >> 6;          // 0..7
    const int rg = wvAll >> 1;         // row group 0..3 (16 rows each)
    const int half = wvAll & 1;        // column half
    const int l = t & 63;
    const int lhi = l >> 4, llo = l & 15;
    const int jbase = half * 7;        // tiles jbase..jbase+6 (half1: 7..12 => 6 tiles)
    const int rbase = blockIdx.x * 64 + rg * 16;
    f32x4 accA[7], accB[7];
#pragma unroll
    for (int j = 0; j < 7; ++j) { accA[j] = f32x4{0.f, 0.f, 0.f, 0.f}; accB[j] = f32x4{0.f, 0.f, 0.f, 0.f}; }
    const short* pa = pA + (size_t)(rbase + llo) * 224 + lhi * 8;
    const short* pb = pB + (size_t)(rbase + llo) * 224 + lhi * 8;
#pragma unroll
    for (int kt = 0; kt < 7; ++kt) {
        bf16x8 a1 = *(const bf16x8*)(pa + kt * 32);
        bf16x8 a2 = *(const bf16x8*)(pb + kt * 32);
#pragma unroll
        for (int j = 0; j < 7; ++j) {
            if (jbase + j < 13) {
                bf16x8 b1 = *(const bf16x8*)(Wi + (size_t)((jbase + j) * 16 + llo) * 224 + kt * 32 + lhi * 8);
                accA[j] = __builtin_amdgcn_mfma_f32_16x16x32_bf16(a1, b1, accA[j], 0, 0, 0);
                bf16x8 b2 = *(const bf16x8*)(Wo + (size_t)((jbase + j) * 16 + llo) * 224 + kt * 32 + lhi * 8);
                accB[j] = __builtin_amdgcn_mfma_f32_16x16x32_bf16(a2, b2, accB[j], 0, 0, 0);
            }
        }
    }
    // entity residual (hop2 only)
    f32x4 accR[7];
    if (!HOP1) {
#pragma unroll
        for (int j = 0; j < 7; ++j) accR[j] = f32x4{0.f, 0.f, 0.f, 0.f};
        const short* xr = xnb + (size_t)(rbase + llo) * 112 + lhi * 8;
#pragma unroll
        for (int kt = 0; kt < 4; ++kt) {
            bf16x8 a = *(const bf16x8*)(xr + kt * 32);
#pragma unroll
            for (int j = 0; j < 7; ++j) {
                if (jbase + j < 13) {
                    bf16x8 b = *(const bf16x8*)(Went + (size_t)((jbase + j) * 16 + llo) * 128 + kt * 32 + lhi * 8);
                    accR[j] = __builtin_amdgcn_mfma_f32_16x16x32_bf16(a, b, accR[j], 0, 0, 0);
                }
            }
        }
    }
    const int r0 = rbase + lhi * 4;
    const int rrb = rg * 16 + lhi * 4;
    float blv = bl[0];
    // phase A: lambda logit partials
#pragma unroll
    for (int e = 0; e < 4; ++e) {
        float lp = 0.f;
#pragma unroll
        for (int j = 0; j < 7; ++j) {
            int d = (jbase + j) * 16 + llo;
            if (jbase + j < 13 && d < 200)
                lp += Wl[d] * (accA[j][e] + bi[d]) + Wl[200 + d] * (accB[j][e] + bo[d]);
        }
        lp = rowSum16(lp);
        if (llo == 0) lpS[half][rrb + e] = lp;
    }
    __syncthreads();
    // phase B: lambda, elu, norm partials
    float lamAll[4];
#pragma unroll
    for (int e = 0; e < 4; ++e) {
        float lam = 1.f / (1.f + expf(-(lpS[0][rrb + e] + lpS[1][rrb + e] + blv)));
        lamAll[e] = lam;
        float ss = 0.f;
#pragma unroll
        for (int j = 0; j < 7; ++j) {
            int d = (jbase + j) * 16 + llo;
            if (jbase + j < 13 && d < 200) {
                float vi = accA[j][e] + bi[d];
                float vo = accB[j][e] + bo[d];
                float hv = eluf(lam * vi + (1.f - lam) * vo);
                ss += hv * hv;
            }
        }
        ss = rowSum16(ss);
        if (llo == 0) ssS[half][rrb + e] = ss;
    }
    __syncthreads();
    // phase C: final write (+ hop2 attention dots in hop1 mode)
#pragma unroll
    for (int e = 0; e < 4; ++e) {
        int r = r0 + e;
        if (r >= rows) continue;
        float inv = 1.f / fmaxf(sqrtf(ssS[0][rrb + e] + ssS[1][rrb + e]), WEPS);
        float lam = lamAll[e];
        float ri = 0.f, ci = 0.f, ro = 0.f, co = 0.f;
#pragma unroll
        for (int j = 0; j < 7; ++j) {
            if (jbase + j >= 13) continue;
            int d = (jbase + j) * 16 + llo;
            if (d < 200) {
                float vi = accA[j][e] + bi[d];
                float vo = accB[j][e] + bo[d];
                float val = eluf(lam * vi + (1.f - lam) * vo) * inv;
                if (HOP1) {
                    h1b[(size_t)r * 224 + d] = f2bf(val);
                    ri += val * wa2i[d]; ci += val * wa2i[200 + d];
                    ro += val * wa2o[d]; co += val * wa2o[200 + d];
                } else {
                    outf[(size_t)r * 200 + d] = val + accR[j][e];
                }
            } else if (HOP1) {
                h1b[(size_t)r * 224 + d] = 0;   // d in [200,208)
            }
        }
        if (HOP1) {
            if (half) h1b[(size_t)r * 224 + 208 + llo] = 0;
            ri = rowSum16(ri); ci = rowSum16(ci); ro = rowSum16(ro); co = rowSum16(co);
            if (llo == 0) {
                dotS[half][rrb + e][0] = ri; dotS[half][rrb + e][1] = ci;
                dotS[half][rrb + e][2] = ro; dotS[half][rrb + e][3] = co;
            }
        }
    }
    if (HOP1) {
        __syncthreads();
        if (half == 0 && llo == 0) {
#pragma unroll
            for (int e = 0; e < 4; ++e) {
                int r = r0 + e;
                if (r < rows) {
                    nd2[r] = f32x4{dotS[0][rrb + e][0] + dotS[1][rrb + e][0],
                                   dotS[0][rrb + e][1] + dotS[1][rrb + e][1],
                                   dotS[0][rrb + e][2] + dotS[1][rrb + e][2],
                                   dotS[0][rrb + e][3] + dotS[1][rrb + e][3]};
                }
            }
        }
    }
}

// ---------------- relation GEMM: fused bias + bf16 gp write + packed hop2 gdots (lda 416) ----------------
__launch_bounds__(256)
__global__ void k_mgemm_rel(const short* __restrict__ A, const short* __restrict__ Wb,
                            const float* __restrict__ brf,
                            short* __restrict__ gout, const float* __restrict__ wai,
                            const float* __restrict__ wao,
                            f32x2* __restrict__ gd2, int rows) {
    constexpr int KSTEPS = 13, LDW = KSTEPS * 32;
    const int t = threadIdx.x;
    const int wv = t >> 6, l = t & 63;
    const int lhi = l >> 4, llo = l & 15;
    const int rbase = blockIdx.x * 64 + wv * 16;
    f32x4 acc[13];
#pragma unroll
    for (int j = 0; j < 13; ++j) acc[j] = f32x4{0.f, 0.f, 0.f, 0.f};
    const short* arow = A + (size_t)(rbase + llo) * 416 + lhi * 8;
#pragma unroll
    for (int kt = 0; kt < KSTEPS; ++kt) {
        bf16x8 a = *(const bf16x8*)(arow + kt * 32);
#pragma unroll
        for (int j = 0; j < 13; ++j) {
            bf16x8 b = *(const bf16x8*)(Wb + (size_t)(j * 16 + llo) * LDW + kt * 32 + lhi * 8);
            acc[j] = __builtin_amdgcn_mfma_f32_16x16x32_bf16(a, b, acc[j], 0, 0, 0);
        }
    }
    const int r0 = rbase + lhi * 4;
#pragma unroll
    for (int e = 0; e < 4; ++e) {
        int r = r0 + e;
        if (r >= rows) continue;
        short* pr = gout + (size_t)r * 224;
        float gi = 0.f, go = 0.f;
#pragma unroll
        for (int j = 0; j < 13; ++j) {
            int d = j * 16 + llo;
            if (d < 200) {
                float val = acc[j][e] + brf[d];
                pr[d] = f2bf(val);
                gi += val * wai[400 + d];
                go += val * wao[400 + d];
            } else {
                pr[d] = 0;   // d in [200,208)
            }
        }
        pr[208 + llo] = 0;
        gi = rowSum16(gi); go = rowSum16(go);
        if (llo == 0) gd2[r] = f32x2{gi, go};
    }
}

// ---------------- weight prep ----------------
__global__ void k_prepw(const float* __restrict__ W, int ldW, int koff, int Klen, int span,
                        int mode, short* __restrict__ Wb, int ldWb, int dst) {
    int id = blockIdx.x * 256 + threadIdx.x;
    int tot = 208 * span;
    if (id >= tot) return;
    int d = id / span, k = id - d * span;
    float v = 0.f;
    if (d < 200) {
        if (mode == 0) { if (k < Klen) v = W[(size_t)d * ldW + koff + k]; }
        else { int h = d / 100; int kk = k - h * 112; if (kk >= 0 && kk < Klen) v = W[(size_t)d * ldW + koff + kk]; }
    }
    Wb[(size_t)d * ldWb + dst + k] = f2bf(v);
}

// combined [Wr | pad | Wf] -> bf16 [208][416]  (cols 0..99 = Wr, 112..411 = Wf)
__global__ void k_prepwrf(const float* __restrict__ Wr, const float* __restrict__ Wf,
                          short* __restrict__ Wb) {
    int id = blockIdx.x * 256 + threadIdx.x;
    if (id >= 208 * 416) return;
    int d = id / 416, k = id - d * 416;
    float v = 0.f;
    if (d < 200) {
        if (k < 100) v = Wr[(size_t)d * 100 + k];
        else if (k >= 112 && k < 412) v = Wf[(size_t)d * 300 + (k - 112)];
    }
    Wb[id] = f2bf(v);
}

__global__ void k_brf(const float* __restrict__ br, const float* __restrict__ bf,
                      float* __restrict__ brf) {
    int d = threadIdx.x;
    if (d < 200) brf[d] = br[d] + bf[d];
}

// ---------------- relation layer: block per type, 384 threads (all gathers from bf16 tables) ----------------
__global__ void k_gedges_b(const int* __restrict__ rsT, const int* __restrict__ csT,
                           const int* __restrict__ offsT,
                           const short* __restrict__ xnb,
                           const short* __restrict__ gbf, short* __restrict__ gcomb, int M) {
    __shared__ float red[6];
    int m = blockIdx.x, t = threadIdx.x;
    int o = offsT[m];
    int deg = offsT[m + 1] - o;
    float acc = 0.f;
    if (t < 128) {
        int d = t; bool ok = d < 100;
        for (int i = 0; i < deg; ++i) {
            int r = rsT[o + i];
            if (ok) acc += bf2f(xnb[(size_t)r * 112 + d]);
        }
    } else if (t < 256) {
        int d = t - 128; bool ok = d < 100;
        for (int i = 0; i < deg; ++i) {
            int c = csT[o + i];
            if (ok) acc += bf2f(xnb[(size_t)c * 112 + d]);
        }
    } else {
        int d = t - 256;
        if (d < 100) acc = (float)deg * bf2f(gbf[(size_t)m * 112 + d]);
    }
    float sq = waveSum(acc * acc);
    if ((t & 63) == 0) red[t >> 6] = sq;
    __syncthreads();
    float s2 = red[0] + red[1] + red[2] + red[3] + red[4] + red[5];
    float inv = 1.f / fmaxf(sqrtf(s2), WEPS);
    short* orow = gcomb + (size_t)m * 416 + 112;
    if (t < 128) {
        if (t < 100) orow[t] = f2bf(eluf(acc * inv));
    } else if (t < 256) {
        int d = t - 128;
        if (d < 100) orow[100 + d] = f2bf(eluf(acc * inv));
    } else {
        int d = t - 256;
        if (d < 100) orow[200 + d] = f2bf(eluf(acc * inv));
        else if (d < 104) orow[200 + d] = 0;   // pad cols 300..303
    }
}

// ---------------- host launch ----------------
extern "C" void kernel_launch(void* const* d_in, const int* in_sizes, int n_in,
                              void* d_out, int out_size, void* d_ws, size_t ws_size,
                              hipStream_t stream) {
    const int* eidx   = (const int*)d_in[0];
    const int* etype  = (const int*)d_in[1];
    const float* x    = (const float*)d_in[5];
    const float* g    = (const float*)d_in[6];
    const float* W_in1  = (const float*)d_in[7];
    const float* att_in1 = (const float*)d_in[8];
    const float* W_out1 = (const float*)d_in[9];
    const float* att_out1 = (const float*)d_in[10];
    const float* Wi1 = (const float*)d_in[11]; const float* bi1 = (const float*)d_in[12];
    const float* Wo1 = (const float*)d_in[13]; const float* bo1 = (const float*)d_in[14];
    const float* Wl1 = (const float*)d_in[15]; const float* bl1 = (const float*)d_in[16];
    const float* Wr  = (const float*)d_in[17]; const float* br  = (const float*)d_in[18];
    const float* Wf  = (const float*)d_in[19]; const float* bf  = (const float*)d_in[20];
    const float* W_in2  = (const float*)d_in[21]; const float* att_in2 = (const float*)d_in[22];
    const float* W_out2 = (const float*)d_in[23]; const float* att_out2 = (const float*)d_in[24];
    const float* Wi2 = (const float*)d_in[25]; const float* bi2 = (const float*)d_in[26];
    const float* Wo2 = (const float*)d_in[27]; const float* bo2 = (const float*)d_in[28];
    const float* Wl2 = (const float*)d_in[29]; const float* bl2 = (const float*)d_in[30];
    const float* W_ent = (const float*)d_in[31];

    const int E = in_sizes[1];
    const int N = in_sizes[5] / 100;
    const int M = in_sizes[6] / 100;
    const int Mr = (M + 63) & ~63;
    float* out = (float*)d_out;
    const int* row = eidx;
    const int* col = eidx + E;

    char* w = (char*)d_ws;
    size_t off_b = 0;
    auto alloc = [&](size_t bytes) -> void* {
        void* p = w + off_b;
        off_b += (bytes + 255) & ~(size_t)255;
        return p;
    };
    short* h1_bf = (short*)alloc((size_t)(N + 64) * 224 * 2);
    short* xn_bf = (short*)alloc((size_t)(N + 64) * 112 * 2);
    short* g_bf  = (short*)alloc((size_t)M * 112 * 2);
    short* gp_bf = (short*)alloc((size_t)Mr * 224 * 2);
    int* offs_in = (int*)alloc((size_t)(N + 1) * 4);
    int* offs_out= (int*)alloc((size_t)(N + 1) * 4);
    int* offsT   = (int*)alloc((size_t)(M + 1) * 4);
    int* nbrS_in = (int*)alloc((size_t)E * 4);
    int* etS_in  = (int*)alloc((size_t)E * 4);
    int* keyS_in = (int*)alloc((size_t)E * 4);
    int* nbrS_out= (int*)alloc((size_t)E * 4);
    int* etS_out = (int*)alloc((size_t)E * 4);
    int* keyS_out= (int*)alloc((size_t)E * 4);
    int* rsT     = (int*)alloc((size_t)E * 4);
    int* csT     = (int*)alloc((size_t)E * 4);
    int* cnt     = (int*)alloc((size_t)N * 4);
    int* cur     = (int*)alloc((size_t)N * 4);
    int* bsum    = (int*)alloc((size_t)64 * 4);
    float* wa1_in = (float*)alloc((size_t)640 * 4);
    float* wa1_out= (float*)alloc((size_t)640 * 4);
    float* wa2_in = (float*)alloc((size_t)640 * 4);
    float* wa2_out= (float*)alloc((size_t)640 * 4);
    f32x4* nd1i  = (f32x4*)alloc((size_t)N * 16);
    f32x4* nd1o  = (f32x4*)alloc((size_t)N * 16);
    f32x4* nd2   = (f32x4*)alloc((size_t)N * 16);
    float* gdot_in = (float*)alloc((size_t)M * 2 * 4);
    float* gdot_out= (float*)alloc((size_t)M * 2 * 4);
    f32x2* gd2   = (f32x2*)alloc((size_t)M * 8);
    float* ewS_in  = (float*)alloc((size_t)E * 2 * 4);
    float* ewS_out = (float*)alloc((size_t)E * 2 * 4);
    // relation A buffer [Mr][416]: cols 0..111 g bf16(+pad), 112..415 ge_n bf16(+pad)
    short* gcomb   = (short*)alloc((size_t)Mr * 416 * 2);
    // bf16 weight buffers
    short* Wc_in1  = (short*)alloc((size_t)208 * 576 * 2);
    short* Wc_out1 = (short*)alloc((size_t)208 * 576 * 2);
    short* Wc_in2  = (short*)alloc((size_t)208 * 672 * 2);
    short* Wc_out2 = (short*)alloc((size_t)208 * 672 * 2);
    short* Wm_i1   = (short*)alloc((size_t)208 * 224 * 2);
    short* Wm_o1   = (short*)alloc((size_t)208 * 224 * 2);
    short* Wm_i2   = (short*)alloc((size_t)208 * 224 * 2);
    short* Wm_o2   = (short*)alloc((size_t)208 * 224 * 2);
    short* Wb_ent  = (short*)alloc((size_t)208 * 128 * 2);
    short* Wrf_b   = (short*)alloc((size_t)208 * 416 * 2);
    float* brf     = (float*)alloc((size_t)200 * 4);

    // chunk buffers: per-row 896(Ac) + 448(postA) + 448(postB) = 1792 B (uncapped C)
    if (off_b >= ws_size) return;
    size_t rem = ws_size - off_b;
    long long Cll = (long long)(rem / 1920);
    long long Nr64 = ((long long)N + 63) & ~63LL;
    int C = (int)(Cll > Nr64 ? Nr64 : Cll);
    C &= ~63;
    if (C < 64) return;
    short* Ac    = (short*)alloc((size_t)C * 448 * 2);
    short* postA = (short*)alloc((size_t)C * 224 * 2);
    short* postB = (short*)alloc((size_t)C * 224 * 2);
    if (off_b > ws_size) return;

    const int gE = (E + 255) / 256;
    const int gN4 = (N + 3) / 4;
    const int gM4 = (M + 3) / 4;
    const int gM64 = (M + 63) / 64;

    // zero pad cols of post buffers + pad rows of feature tables (tail-tile reads)
    hipMemsetAsync(postA, 0, (size_t)C * 224 * 2, stream);
    hipMemsetAsync(postB, 0, (size_t)C * 224 * 2, stream);
    hipMemsetAsync(xn_bf + (size_t)N * 112, 0, (size_t)64 * 112 * 2, stream);
    hipMemsetAsync(h1_bf + (size_t)N * 224, 0, (size_t)64 * 224 * 2, stream);

    // ---- weight prep ----
    auto gsp = [](int span) { return (208 * span + 255) / 256; };
    k_prepw<<<gsp(224), 256, 0, stream>>>(W_in1, 300, 0, 100, 224, 1, Wc_in1, 576, 0);
    k_prepw<<<gsp(224), 256, 0, stream>>>(W_in1, 300, 200, 100, 224, 1, Wc_in1, 576, 224);
    k_prepw<<<gsp(128), 256, 0, stream>>>(W_in1, 300, 100, 100, 128, 0, Wc_in1, 576, 448);
    k_prepw<<<gsp(224), 256, 0, stream>>>(W_out1, 300, 100, 100, 224, 1, Wc_out1, 576, 0);
    k_prepw<<<gsp(224), 256, 0, stream>>>(W_out1, 300, 200, 100, 224, 1, Wc_out1, 576, 224);
    k_prepw<<<gsp(128), 256, 0, stream>>>(W_out1, 300, 0, 100, 128, 0, Wc_out1, 576, 448);
    k_prepw<<<gsp(224), 256, 0, stream>>>(W_in2, 600, 0, 200, 224, 0, Wc_in2, 672, 0);
    k_prepw<<<gsp(224), 256, 0, stream>>>(W_in2, 600, 400, 200, 224, 0, Wc_in2, 672, 224);
    k_prepw<<<gsp(224), 256, 0, stream>>>(W_in2, 600, 200, 200, 224, 0, Wc_in2, 672, 448);
    k_prepw<<<gsp(224), 256, 0, stream>>>(W_out2, 600, 200, 200, 224, 0, Wc_out2, 672, 0);
    k_prepw<<<gsp(224), 256, 0, stream>>>(W_out2, 600, 400, 200, 224, 0, Wc_out2, 672, 224);
    k_prepw<<<gsp(224), 256, 0, stream>>>(W_out2, 600, 0, 200, 224, 0, Wc_out2, 672, 448);
    k_prepw<<<gsp(224), 256, 0, stream>>>(Wi1, 200, 0, 200, 224, 0, Wm_i1, 224, 0);
    k_prepw<<<gsp(224), 256, 0, stream>>>(Wo1, 200, 0, 200, 224, 0, Wm_o1, 224, 0);
    k_prepw<<<gsp(224), 256, 0, stream>>>(Wi2, 200, 0, 200, 224, 0, Wm_i2, 224, 0);
    k_prepw<<<gsp(224), 256, 0, stream>>>(Wo2, 200, 0, 200, 224, 0, Wm_o2, 224, 0);
    k_prepw<<<gsp(128), 256, 0, stream>>>(W_ent, 100, 0, 100, 128, 0, Wb_ent, 128, 0);
    k_prepwrf<<<gsp(416), 256, 0, stream>>>(Wr, Wf, Wrf_b);
    k_brf<<<1, 256, 0, stream>>>(br, bf, brf);

    // ---- CSR builds with sorted payloads ----
    int nbN = (N + SCAN_CHUNK - 1) / SCAN_CHUNK;
    int nbM = (M + SCAN_CHUNK - 1) / SCAN_CHUNK;
    hipMemsetAsync(cnt, 0, (size_t)N * 4, stream);
    k_count<<<gE, 256, 0, stream>>>(col, cnt, E);
    k_blocksum<<<nbN, 256, 0, stream>>>(cnt, bsum, N);
    k_scanwrite<<<nbN, 256, 0, stream>>>(cnt, bsum, offs_in, cur, N, nbN);
    k_scatter3<<<gE, 256, 0, stream>>>(col, row, etype, cur, nbrS_in, etS_in, keyS_in, E);

    hipMemsetAsync(cnt, 0, (size_t)N * 4, stream);
    k_count<<<gE, 256, 0, stream>>>(row, cnt, E);
    k_blocksum<<<nbN, 256, 0, stream>>>(cnt, bsum, N);
    k_scanwrite<<<nbN, 256, 0, stream>>>(cnt, bsum, offs_out, cur, N, nbN);
    k_scatter3<<<gE, 256, 0, stream>>>(row, col, etype, cur, nbrS_out, etS_out, keyS_out, E);

    hipMemsetAsync(cnt, 0, (size_t)M * 4, stream);
    k_count<<<gE, 256, 0, stream>>>(etype, cnt, E);
    k_blocksum<<<nbM, 256, 0, stream>>>(cnt, bsum, M);
    k_scanwrite<<<nbM, 256, 0, stream>>>(cnt, bsum, offsT, cur, M, nbM);
    k_scatter2<<<gE, 256, 0, stream>>>(etype, cur, rsT, csT, row, col, E);

    // ---- attention vectors ----
    k_watt<<<(600 + 255) / 256, 256, 0, stream>>>(att_in1, W_in1, wa1_in, 2, 100, 300);
    k_watt<<<(600 + 255) / 256, 256, 0, stream>>>(att_out1, W_out1, wa1_out, 2, 100, 300);
    k_watt<<<(600 + 255) / 256, 256, 0, stream>>>(att_in2, W_in2, wa2_in, 1, 200, 600);
    k_watt<<<(600 + 255) / 256, 256, 0, stream>>>(att_out2, W_out2, wa2_out, 1, 200, 600);

    // ---- fused prep: one pass over x, one pass over g ----
    k_nodeprep<<<gN4, 256, 0, stream>>>(x, xn_bf, wa1_in, wa1_out, nd1i, nd1o, N);
    k_gprep<<<gM4, 256, 0, stream>>>(g, g_bf, gcomb, wa1_in, wa1_out, gdot_in, gdot_out, M);
    k_ewh1<<<(2 * E * 2 + 255) / 256, 256, 0, stream>>>(nbrS_in, keyS_in, etS_in,
                                                        nbrS_out, keyS_out, etS_out,
                                                        nd1i, nd1o, gdot_in, gdot_out,
                                                        ewS_in, ewS_out, E);

    for (int n0 = 0; n0 < N; n0 += C) {
        int rows = (N - n0 < C) ? (N - n0) : C;
        int n1 = n0 + rows;
        int ga = (rows + 3) / 4;
        int gb = (rows + 63) / 64;
        // in-direction (ends=col, nbr=row, self=col)
        k_agg<false><<<ga, 256, 0, stream>>>(offs_in, nbrS_in, etS_in, ewS_in, xn_bf, g_bf, Ac, n0, n1);
        k_mgemm_post<4, 2><<<gb, 256, 0, stream>>>(Ac, Wc_in1, xn_bf + (size_t)n0 * 112, 112,
                                                   offs_in + n0, postA, rows);
        // out-direction (ends=row, nbr=col, self=row)
        k_agg<false><<<ga, 256, 0, stream>>>(offs_out, nbrS_out, etS_out, ewS_out, xn_bf, g_bf, Ac, n0, n1);
        k_mgemm_post<4, 2><<<gb, 256, 0, stream>>>(Ac, Wc_out1, xn_bf + (size_t)n0 * 112, 112,
                                                   offs_out + n0, postB, rows);
        k_mergemm2<true><<<gb, 512, 0, stream>>>(postA, postB, Wm_i1, Wm_o1, bi1, bo1, Wl1, bl1,
                                                 nullptr, nullptr,
                                                 nullptr, h1_bf + (size_t)n0 * 224,
                                                 wa2_in, wa2_out, nd2 + n0, rows);
    }

    // ---- relation layer: segment sum + fused GEMM (bf16 gp + packed hop2 gdots) ----
    k_gedges_b<<<M, 384, 0, stream>>>(rsT, csT, offsT, xn_bf, g_bf, gcomb, M);
    k_mgemm_rel<<<gM64, 256, 0, stream>>>(gcomb, Wrf_b, brf, gp_bf, wa2_in, wa2_out, gd2, M);

    // ---- hop 2 edge weights (packed node/g dots) ----
    k_ewh2<<<(2 * E + 255) / 256, 256, 0, stream>>>(nbrS_in, keyS_in, etS_in,
                                                    nbrS_out, keyS_out, etS_out,
                                                    nd2, gd2, ewS_in, ewS_out, E);

    for (int n0 = 0; n0 < N; n0 += C) {
        int rows = (N - n0 < C) ? (N - n0) : C;
        int n1 = n0 + rows;
        int ga = (rows + 3) / 4;
        int gb = (rows + 63) / 64;
        k_agg<true><<<ga, 256, 0, stream>>>(offs_in, nbrS_in, etS_in, ewS_in, h1_bf, gp_bf, Ac, n0, n1);
        k_mgemm_post<7, 1><<<gb, 256, 0, stream>>>(Ac, Wc_in2, h1_bf + (size_t)n0 * 224, 224,
                                                   offs_in + n0, postA, rows);
        k_agg<true><<<ga, 256, 0, stream>>>(offs_out, nbrS_out, etS_out, ewS_out, h1_bf, gp_bf, Ac, n0, n1);
        k_mgemm_post<7, 1><<<gb, 256, 0, stream>>>(Ac, Wc_out2, h1_bf + (size_t)n0 * 224, 224,
                                                   offs_out + n0, postB, rows);
        k_mergemm2<false><<<gb, 512, 0, stream>>>(postA, postB, Wm_i2, Wm_o2, bi2, bo2, Wl2, bl2,
                                                  xn_bf + (size_t)n0 * 112, Wb_ent,
                                                  out + (size_t)n0 * 200, nullptr,
                                                  nullptr, nullptr, nullptr, rows);
    }
}